// Round 10
// baseline (486.791 us; speedup 1.0000x reference)
//
#include <hip/hip_runtime.h>
#include <hip/hip_bf16.h>

typedef unsigned short u16;
typedef unsigned int u32;

using bf16x8 = __bf16 __attribute__((ext_vector_type(8)));
using s16x8  = short  __attribute__((ext_vector_type(8)));
using f32x4  = float  __attribute__((ext_vector_type(4)));

#define DEV static __device__ __forceinline__

constexpr int T_ = 2048, D_ = 1024;
constexpr int C_ = 64, NC_ = 32;   // chunk length / count
constexpr float EPS_ = 1e-5f;

DEV float bf2f(u16 u) { return __uint_as_float(((u32)u) << 16); }
DEV u16 f2bf(float f) {
  u32 u = __float_as_uint(f);
  return (u16)((u + 0x7fffu + ((u >> 16) & 1u)) >> 16);
}
DEV float swishf(float x) { return x / (1.f + __expf(-x)); }
DEV f32x4 zero4() { f32x4 z = {0.f, 0.f, 0.f, 0.f}; return z; }

// fragment loader: operand stored [outdim][contract] row-major, 16B/lane
DEV bf16x8 ld8(const u16* p, int ld, int r0, int k0, int lane) {
  return *(const bf16x8*)(p + (size_t)(r0 + (lane & 15)) * ld +
                          (size_t)(k0 + ((lane >> 4) << 3)));
}
DEV f32x4 MFMA(bf16x8 a, bf16x8 b, f32x4 c) {
  return __builtin_amdgcn_mfma_f32_16x16x32_bf16(a, b, c, 0, 0, 0);
}
// direct global->LDS DMA, 16B per lane; LDS dest = wave-uniform base + lane*16
DEV void gld_lds16(const void* g, void* l) {
  __builtin_amdgcn_global_load_lds(
      (const __attribute__((address_space(1))) unsigned int*)g,
      (__attribute__((address_space(3))) unsigned int*)l, 16, 0, 0);
}

// ---------------- K0: fp32 -> bf16 weight conversion (5 weights fused) ----------------
__global__ __launch_bounds__(256) void k_cvt5(
    const float* __restrict__ s0, const float* __restrict__ s1,
    const float* __restrict__ s2, const float* __restrict__ s3,
    const float* __restrict__ s4, u16* __restrict__ d0, u16* __restrict__ d1,
    u16* __restrict__ d2, u16* __restrict__ d3, u16* __restrict__ d4) {
  const int wsel = blockIdx.x >> 10;
  const float* s = (wsel == 0) ? s0 : (wsel == 1) ? s1 : (wsel == 2) ? s2
                   : (wsel == 3) ? s3 : s4;
  u16* d = (wsel == 0) ? d0 : (wsel == 1) ? d1 : (wsel == 2) ? d2
           : (wsel == 3) ? d3 : d4;
  const int i = (blockIdx.x & 1023) * 256 + threadIdx.x;
  float4 v = ((const float4*)s)[i];
  uint2 o;
  o.x = (u32)f2bf(v.x) | ((u32)f2bf(v.y) << 16);
  o.y = (u32)f2bf(v.z) | ((u32)f2bf(v.w) << 16);
  ((uint2*)d)[i] = o;
}

// ---------------- K1: RMSNorm (fp32 in -> bf16 h) ----------------
__global__ __launch_bounds__(256) void k_rmsnorm(const float* __restrict__ x,
                                                 const float* __restrict__ w,
                                                 u16* __restrict__ h) {
  const int row = blockIdx.x, tid = threadIdx.x;
  float4 v = ((const float4*)(x + (size_t)row * D_))[tid];
  float ss = v.x * v.x + v.y * v.y + v.z * v.z + v.w * v.w;
#pragma unroll
  for (int d = 32; d >= 1; d >>= 1) ss += __shfl_xor(ss, d, 64);
  __shared__ float red[4];
  if ((tid & 63) == 0) red[tid >> 6] = ss;
  __syncthreads();
  float rs = rsqrtf((red[0] + red[1] + red[2] + red[3]) * (1.f / D_) + EPS_);
  float4 wv = ((const float4*)w)[tid];
  uint2 o;
  o.x = (u32)f2bf(v.x * rs * wv.x) | ((u32)f2bf(v.y * rs * wv.y) << 16);
  o.y = (u32)f2bf(v.z * rs * wv.z) | ((u32)f2bf(v.w * rs * wv.w) << 16);
  *(uint2*)(h + (size_t)row * D_ + tid * 4) = o;
}

// ---------------- K6: swish + RMSNorm (bf16 in -> bf16) ----------------
__global__ __launch_bounds__(256) void k_swishnorm(const u16* __restrict__ x,
                                                   const float* __restrict__ w,
                                                   u16* __restrict__ o) {
  const int row = blockIdx.x, tid = threadIdx.x;
  uint2 pk = *(const uint2*)(x + (size_t)row * D_ + tid * 4);
  float v0 = swishf(bf2f((u16)(pk.x & 0xffff))), v1 = swishf(bf2f((u16)(pk.x >> 16)));
  float v2 = swishf(bf2f((u16)(pk.y & 0xffff))), v3 = swishf(bf2f((u16)(pk.y >> 16)));
  float ss = v0 * v0 + v1 * v1 + v2 * v2 + v3 * v3;
#pragma unroll
  for (int d = 32; d >= 1; d >>= 1) ss += __shfl_xor(ss, d, 64);
  __shared__ float red[4];
  if ((tid & 63) == 0) red[tid >> 6] = ss;
  __syncthreads();
  float rs = rsqrtf((red[0] + red[1] + red[2] + red[3]) * (1.f / D_) + EPS_);
  float4 wv = ((const float4*)w)[tid];
  uint2 ov;
  ov.x = (u32)f2bf(v0 * rs * wv.x) | ((u32)f2bf(v1 * rs * wv.y) << 16);
  ov.y = (u32)f2bf(v2 * rs * wv.z) | ((u32)f2bf(v3 * rs * wv.w) << 16);
  *(uint2*)(o + (size_t)row * D_ + tid * 4) = ov;
}

// ---------------- K2: fused 4-weight projection GEMM, counted-vmcnt pipeline --------
// R5's proven version (146.2 us), split into two half-M launches for rocprof
// visibility of tail kernels.
#define WAITV6() asm volatile("s_waitcnt vmcnt(6)" ::: "memory")
#define WAITV0() asm volatile("s_waitcnt vmcnt(0)" ::: "memory")
__global__ __launch_bounds__(256, 2) void k_gemm4(
    const u16* __restrict__ A, const u16* __restrict__ w0,
    const u16* __restrict__ w1, const u16* __restrict__ w2,
    const u16* __restrict__ w3, u16* __restrict__ oq, u16* __restrict__ okk,
    u16* __restrict__ ov, float* __restrict__ og, const int mb) {
  __shared__ __align__(16) u16 As[3][128 * 32];   // 3 x 8KB
  __shared__ __align__(16) u16 Bs[3][4][64 * 32]; // 3 x 16KB  (72KB total)
  const int m0 = mb + blockIdx.x * 128, n0 = blockIdx.y * 64;
  const int tid = threadIdx.x, lane = tid & 63, wvi = tid >> 6;
  f32x4 acc[4][2][4];  // [weight][mi][nj]
#pragma unroll
  for (int w = 0; w < 4; w++)
#pragma unroll
    for (int i = 0; i < 2; i++)
#pragma unroll
      for (int j = 0; j < 4; j++) acc[w][i][j] = zero4();
  const int srow = tid >> 2, scb = (tid & 3) * 8;
  const u16* Ag = A + (size_t)(m0 + srow) * 1024 + scb;
  const u16* Wg0 = w0 + (size_t)(n0 + srow) * 1024 + scb;
  const u16* Wg1 = w1 + (size_t)(n0 + srow) * 1024 + scb;
  const u16* Wg2 = w2 + (size_t)(n0 + srow) * 1024 + scb;
  const u16* Wg3 = w3 + (size_t)(n0 + srow) * 1024 + scb;
  const int sofs = (wvi * 16) * 32;  // this wave's 16-row slice in each tile

  auto stage = [&](int buf, int kk) {
    gld_lds16(Ag + kk, &As[buf][sofs]);
    gld_lds16(Ag + kk + 64 * 1024, &As[buf][sofs + 64 * 32]);
    gld_lds16(Wg0 + kk, &Bs[buf][0][sofs]);
    gld_lds16(Wg1 + kk, &Bs[buf][1][sofs]);
    gld_lds16(Wg2 + kk, &Bs[buf][2][sofs]);
    gld_lds16(Wg3 + kk, &Bs[buf][3][sofs]);
  };
  auto compute = [&](int buf) {
    bf16x8 af[2];
#pragma unroll
    for (int i = 0; i < 2; i++)
      af[i] = ld8(As[buf], 32, wvi * 32 + 16 * i, 0, lane);
#pragma unroll
    for (int w = 0; w < 4; w++) {
      bf16x8 bfr[4];
#pragma unroll
      for (int j = 0; j < 4; j++) bfr[j] = ld8(Bs[buf][w], 32, 16 * j, 0, lane);
#pragma unroll
      for (int i = 0; i < 2; i++)
#pragma unroll
        for (int j = 0; j < 4; j++) acc[w][i][j] = MFMA(af[i], bfr[j], acc[w][i][j]);
    }
  };

  stage(0, 0);
  stage(1, 32);
  int b0 = 0, b1 = 1, b2 = 2;
  for (int t = 0; t < 32; ++t) {
    if (t < 31) { WAITV6(); } else { WAITV0(); }
    __builtin_amdgcn_sched_barrier(0);
    __builtin_amdgcn_s_barrier();       // all waves' stage(t) landed; reads of t-1 done
    __builtin_amdgcn_sched_barrier(0);
    if (t + 2 < 32) stage(b2, (t + 2) * 32);  // issue-early prefetch into freed buffer
    __builtin_amdgcn_s_setprio(1);
    compute(b0);
    __builtin_amdgcn_s_setprio(0);
    int tmp = b0; b0 = b1; b1 = b2; b2 = tmp;  // rotate buffers
  }
  const int q4 = lane >> 4, c15 = lane & 15;
#pragma unroll
  for (int w = 0; w < 4; w++)
#pragma unroll
    for (int i = 0; i < 2; i++)
#pragma unroll
      for (int j = 0; j < 4; j++)
#pragma unroll
        for (int r = 0; r < 4; r++) {
          int grow = m0 + wvi * 32 + 16 * i + 4 * q4 + r;
          int gcol = n0 + 16 * j + c15;
          size_t idx = (size_t)grow * 1024 + gcol;
          float val = acc[w][i][j][r];
          if (w < 3) {
            u16* o = (w == 0) ? oq : (w == 1) ? okk : ov;
            o[idx] = f2bf(swishf(val));
          } else {
            float g = (val >= 0.f) ? -log1pf(__expf(-val))
                                   : (val - log1pf(__expf(val)));
            og[idx] = g * (1.0f / 16.0f);
          }
        }
}

// ---------------- K7: round-3 known-good 128x128 GEMM (final projection) ----------------
__global__ __launch_bounds__(256) void k_gemmO(const u16* __restrict__ A,
                                               const u16* __restrict__ W,
                                               float* __restrict__ ofin) {
  __shared__ __align__(16) u16 As[128 * 32];
  __shared__ __align__(16) u16 Bs[128 * 32];
  const int m0 = blockIdx.x * 128, n0 = blockIdx.y * 128;
  const int tid = threadIdx.x, lane = tid & 63, wvi = tid >> 6;
  const int wr = wvi >> 1, wc = wvi & 1;
  f32x4 acc[4][4];
#pragma unroll
  for (int i = 0; i < 4; i++)
#pragma unroll
    for (int j = 0; j < 4; j++) acc[i][j] = zero4();
  const int srow = tid >> 2, scb = (tid & 3) * 8;
  const u16* Ag = A + (size_t)(m0 + srow) * 1024 + scb;
  const u16* Wg = W + (size_t)(n0 + srow) * 1024 + scb;
  u16* AsW = As + (wvi * 16) * 32;
  u16* BsW = Bs + (wvi * 16) * 32;
  for (int kk = 0; kk < 1024; kk += 32) {
    gld_lds16(Ag + kk, AsW);
    gld_lds16(Ag + kk + 64 * 1024, AsW + 64 * 32);
    gld_lds16(Wg + kk, BsW);
    gld_lds16(Wg + kk + 64 * 1024, BsW + 64 * 32);
    __syncthreads();
    bf16x8 af[4], bfr[4];
#pragma unroll
    for (int i = 0; i < 4; i++) af[i] = ld8(As, 32, wr * 64 + 16 * i, 0, lane);
#pragma unroll
    for (int j = 0; j < 4; j++) bfr[j] = ld8(Bs, 32, wc * 64 + 16 * j, 0, lane);
#pragma unroll
    for (int i = 0; i < 4; i++)
#pragma unroll
      for (int j = 0; j < 4; j++) acc[i][j] = MFMA(af[i], bfr[j], acc[i][j]);
    __syncthreads();
  }
  const int q4 = lane >> 4, c15 = lane & 15;
#pragma unroll
  for (int i = 0; i < 4; i++)
#pragma unroll
    for (int j = 0; j < 4; j++)
#pragma unroll
      for (int r = 0; r < 4; r++) {
        int grow = m0 + wr * 64 + 16 * i + 4 * q4 + r;
        int gcol = n0 + wc * 64 + 16 * j + c15;
        ofin[(size_t)grow * 1024 + gcol] = acc[i][j][r];
      }
}

// ---------------- K2b: gates ----------------
__global__ __launch_bounds__(256) void k_gates(float* __restrict__ g_inout,
                                               u16* __restrict__ U_t,
                                               float* __restrict__ Lam) {
  const int c = blockIdx.x, p = blockIdx.y, tid = threadIdx.x;  // tid = m
  const int b = p >> 2, hh = p & 3;
  const int R0 = b * T_ + c * C_, hb = hh * 256;
  float ga = 0.f, ea = 1.f;
  short ubuf[C_];
#pragma unroll
  for (int t = 0; t < C_; t++) {
    size_t gi = (size_t)(R0 + t) * D_ + hb + tid;
    float gv = g_inout[gi];
    ga += gv;
    ea = __expf(ga);
    ubuf[t] = (short)f2bf((1.f - __expf(gv)) * __expf(-ga));
    g_inout[gi] = ea;  // E in place
  }
  Lam[((size_t)p * NC_ + c) * 256 + tid] = ea;
  u16* up = U_t + ((size_t)p * NC_ + c) * (256 * C_) + (size_t)tid * C_;
#pragma unroll
  for (int i = 0; i < 8; i++) {
    s16x8 w;
#pragma unroll
    for (int j = 0; j < 8; j++) w[j] = ubuf[i * 8 + j];
    *(s16x8*)(up + i * 8) = w;
  }
}

// ---------------- K3: per-chunk intra states ----------------
__global__ __launch_bounds__(256) void k_intra(
    const u16* __restrict__ kg, const u16* __restrict__ vg,
    const u16* __restrict__ U_t, const float* __restrict__ Lam,
    u16* __restrict__ Sk, u16* __restrict__ Sv) {
  __shared__ __align__(16) u16 KV[256 * 72];   // K^T then V^T  [d/v][tau]
  __shared__ float LamH[256];
  const int c = blockIdx.x, p = blockIdx.y;
  const int b = p >> 2, hh = p & 3;
  const int R0 = b * T_ + c * C_, hb = hh * 256;
  const int tid = threadIdx.x, lane = tid & 63, wvi = tid >> 6;
  const int q4 = lane >> 4, c15 = lane & 15;
  const size_t chunk = (size_t)p * NC_ + c;
  const u16* Uc = U_t + chunk * (256 * C_);  // [m][64]
  const size_t scBase = chunk * (256 * 256);

  LamH[tid] = Lam[chunk * 256 + tid];
  // stage K^T
  for (int t = 0; t < C_; t++)
    KV[tid * 72 + t] = kg[(size_t)(R0 + t) * D_ + hb + tid];
  __syncthreads();

  // Hk^T: [256 m][256 d]; wave wvi owns m rows [64*wvi, +64)
  for (int cb = 0; cb < 4; cb++) {
    f32x4 acc[4][4];
#pragma unroll
    for (int i = 0; i < 4; i++)
#pragma unroll
      for (int j = 0; j < 4; j++) acc[i][j] = zero4();
#pragma unroll
    for (int ks = 0; ks < 2; ks++) {
      bf16x8 af[4], bfr[4];
#pragma unroll
      for (int i = 0; i < 4; i++) af[i] = ld8(Uc, C_, 64 * wvi + 16 * i, 32 * ks, lane);
#pragma unroll
      for (int j = 0; j < 4; j++) bfr[j] = ld8(KV, 72, 64 * cb + 16 * j, 32 * ks, lane);
#pragma unroll
      for (int i = 0; i < 4; i++)
#pragma unroll
        for (int j = 0; j < 4; j++) acc[i][j] = MFMA(af[i], bfr[j], acc[i][j]);
    }
#pragma unroll
    for (int i = 0; i < 4; i++)
#pragma unroll
      for (int j = 0; j < 4; j++)
#pragma unroll
        for (int r = 0; r < 4; r++) {
          int ml = 64 * wvi + 16 * i + 4 * q4 + r;
          int dd = 64 * cb + 16 * j + c15;
          Sk[scBase + (size_t)ml * 256 + dd] = f2bf(acc[i][j][r] * LamH[ml]);
        }
  }
  __syncthreads();

  // stage V^T
  for (int t = 0; t < C_; t++)
    KV[tid * 72 + t] = vg[(size_t)(R0 + t) * D_ + hb + tid];
  __syncthreads();

  // Hv^T: [256 v][256 m]; wave wvi owns v rows [64*wvi, +64)
  for (int cb = 0; cb < 4; cb++) {
    f32x4 acc[4][4];
#pragma unroll
    for (int i = 0; i < 4; i++)
#pragma unroll
      for (int j = 0; j < 4; j++) acc[i][j] = zero4();
#pragma unroll
    for (int ks = 0; ks < 2; ks++) {
      bf16x8 af[4], bfr[4];
#pragma unroll
      for (int i = 0; i < 4; i++) af[i] = ld8(KV, 72, 64 * wvi + 16 * i, 32 * ks, lane);
#pragma unroll
      for (int j = 0; j < 4; j++) bfr[j] = ld8(Uc, C_, 64 * cb + 16 * j, 32 * ks, lane);
#pragma unroll
      for (int i = 0; i < 4; i++)
#pragma unroll
        for (int j = 0; j < 4; j++) acc[i][j] = MFMA(af[i], bfr[j], acc[i][j]);
    }
#pragma unroll
    for (int i = 0; i < 4; i++)
#pragma unroll
      for (int j = 0; j < 4; j++)
#pragma unroll
        for (int r = 0; r < 4; r++) {
          int vv = 64 * wvi + 16 * i + 4 * q4 + r;
          int ml = 64 * cb + 16 * j + c15;
          Sv[scBase + (size_t)vv * 256 + ml] = f2bf(acc[i][j][r] * LamH[ml]);
        }
  }
}

// ---------------- K4: chunk-prefix scan (entering state per chunk, in place) ----------------
__global__ __launch_bounds__(256) void k_scan(u16* __restrict__ Sk,
                                              u16* __restrict__ Sv,
                                              const float* __restrict__ Lam) {
  const int gid = blockIdx.x * 256 + threadIdx.x;  // 0..262143
  const int st = gid >> 17;
  const int w = gid & 131071;
  const int p = w >> 13;
  const int r = (w >> 5) & 255;
  const int c0 = (w & 31) * 8;
  u16* S = st ? Sv : Sk;
  const size_t base = (size_t)p * NC_ * 65536 + (size_t)r * 256 + c0;
  const float* Lp = Lam + (size_t)p * NC_ * 256;
  float acc[8] = {0, 0, 0, 0, 0, 0, 0, 0};
  for (int c = 0; c < NC_; c++) {
    s16x8 in = *(const s16x8*)(S + base + (size_t)c * 65536);
    s16x8 ov;
#pragma unroll
    for (int j = 0; j < 8; j++) ov[j] = (short)f2bf(acc[j]);
    *(s16x8*)(S + base + (size_t)c * 65536) = ov;  // entering state S_c
    if (st == 0) {
      float lam = Lp[c * 256 + r];
#pragma unroll
      for (int j = 0; j < 8; j++) acc[j] = acc[j] * lam + bf2f((u16)in[j]);
    } else {
#pragma unroll
      for (int j = 0; j < 8; j++) {
        float lam = Lp[c * 256 + c0 + j];
        acc[j] = acc[j] * lam + bf2f((u16)in[j]);
      }
    }
  }
}

// ---------------- K5: per-chunk output — 8-wave split (R10) ----------------
// R9 showed occupancy is GRID-limited (512 blocks = 2/CU, 25% cap). This version
// uses 512 threads / 8 waves per chunk: wave = (t-tile tw, group gh). P1 splits
// tau-tiles; P2 splits the m-dim (zac[16]->zac[8]); P3 is a two-half softmax
// merged via a small LDS (max,sum) exchange (flash-style); P5 splits tau-tiles
// (full-m accumulation per wave, no cross-wave reduction); P6 splits v-quarters
// across groups with per-group staging. 16 waves/CU (2x TLP), half work/wave.
__global__ __launch_bounds__(512) void k_out(
    const u16* __restrict__ qg, const u16* __restrict__ kg,
    const u16* __restrict__ vg, const u16* __restrict__ U_t,
    const float* __restrict__ Eg, const u16* __restrict__ Sk,
    const u16* __restrict__ Sv, u16* __restrict__ orw) {
  __shared__ __align__(16) char lds[62464];
  u16* As  = (u16*)lds;                 // [64][72]: masked QK^T, later W
  u16* Pt  = (u16*)(lds + 9216);        // [64][264]: P~
  float* SM = (float*)(lds + 43008);    // [64 t][2 gh][2 {mx,sm}] = 1KB
  u16* Ust = (u16*)(lds + 44032);       // [64 tau][72 m-quarter] (P5)
  u16* Vst0 = (u16*)(lds + 44032);      // aliases Ust (P6 group 0)
  u16* Vst1 = (u16*)(lds + 53248);      // [64 v][72 t] (P6 group 1)

  const int c = blockIdx.x, p = blockIdx.y;
  const int b = p >> 2, hh = p & 3;
  const int R0 = b * T_ + c * C_, hb = hh * 256;
  const int tid = threadIdx.x, lane = tid & 63, wvi = tid >> 6;
  const int tw = wvi & 3, gh = wvi >> 2;   // t-tile, m/v-group
  const int q4 = lane >> 4, c15 = lane & 15;
  const u16* qbase = qg + (size_t)R0 * D_ + hb;
  const u16* kbase = kg + (size_t)R0 * D_ + hb;
  const float* Ebase = Eg + (size_t)R0 * D_ + hb;
  const size_t chunk = (size_t)p * NC_ + c;
  const u16* SkC = Sk + chunk * 65536;
  const u16* SvC = Sv + chunk * 65536;
  const u16* Uc = U_t + chunk * (256 * C_);   // [m][64]

  // P1: masked QK^T — wave (tw,gh) computes t-tile tw, tau-tiles {2gh, 2gh+1}
  {
    f32x4 acc[2];
    acc[0] = zero4(); acc[1] = zero4();
#pragma unroll
    for (int ks = 0; ks < 8; ks++) {
      bf16x8 af = ld8(qbase, D_, 16 * tw, 32 * ks, lane);
#pragma unroll
      for (int n = 0; n < 2; n++)
        acc[n] = MFMA(af, ld8(kbase, D_, 16 * (2 * gh + n), 32 * ks, lane), acc[n]);
    }
#pragma unroll
    for (int n = 0; n < 2; n++)
#pragma unroll
      for (int r = 0; r < 4; r++) {
        int t = 16 * tw + 4 * q4 + r, tau = 16 * (2 * gh + n) + c15;
        As[t * 72 + tau] = f2bf(tau <= t ? acc[n][r] : 0.f);
      }
  }
  __syncthreads();

  // P2: zac[8] = E * (As@U + Q@Sk) for own m-half gh
  f32x4 zac[8];
#pragma unroll
  for (int n = 0; n < 8; n++) zac[n] = zero4();
#pragma unroll
  for (int ks = 0; ks < 2; ks++) {
    bf16x8 af = ld8(As, 72, 16 * tw, 32 * ks, lane);
#pragma unroll
    for (int n = 0; n < 8; n++)
      zac[n] = MFMA(af, ld8(Uc, C_, gh * 128 + 16 * n, 32 * ks, lane), zac[n]);
  }
#pragma unroll
  for (int ks = 0; ks < 8; ks++) {
    bf16x8 af = ld8(qbase, D_, 16 * tw, 32 * ks, lane);
#pragma unroll
    for (int n = 0; n < 8; n++)
      zac[n] = MFMA(af, ld8(SkC + (size_t)gh * 128 * 256, 256, 16 * n, 32 * ks, lane),
                    zac[n]);
  }
#pragma unroll
  for (int n = 0; n < 8; n++)
#pragma unroll
    for (int r = 0; r < 4; r++) {
      int t = 16 * tw + 4 * q4 + r;
      zac[n][r] *= Ebase[(size_t)t * D_ + gh * 128 + 16 * n + c15];
    }

  // P3: half-softmax (own 128 m) + cross-group merge via SM
  float pmx[4], psm[4];
#pragma unroll
  for (int r = 0; r < 4; r++) {
    float mx = -3.0e38f;
#pragma unroll
    for (int i = 0; i < 8; i++) mx = fmaxf(mx, zac[i][r]);
    mx = fmaxf(mx, __shfl_xor(mx, 1, 64));
    mx = fmaxf(mx, __shfl_xor(mx, 2, 64));
    mx = fmaxf(mx, __shfl_xor(mx, 4, 64));
    mx = fmaxf(mx, __shfl_xor(mx, 8, 64));
    float sm = 0.f;
#pragma unroll
    for (int i = 0; i < 8; i++) {
      float e = __expf(zac[i][r] - mx);
      zac[i][r] = e;
      sm += e;
    }
    sm += __shfl_xor(sm, 1, 64);
    sm += __shfl_xor(sm, 2, 64);
    sm += __shfl_xor(sm, 4, 64);
    sm += __shfl_xor(sm, 8, 64);
    pmx[r] = mx; psm[r] = sm;
    if (c15 == 0) {
      int t = 16 * tw + 4 * q4 + r;
      SM[t * 4 + gh * 2]     = mx;
      SM[t * 4 + gh * 2 + 1] = sm;
    }
  }
  __syncthreads();
#pragma unroll
  for (int r = 0; r < 4; r++) {
    int t = 16 * tw + 4 * q4 + r;
    float mxo = SM[t * 4 + (1 - gh) * 2];
    float smo = SM[t * 4 + (1 - gh) * 2 + 1];
    float gmx = fmaxf(pmx[r], mxo);
    float sc = __expf(pmx[r] - gmx) /
               (psm[r] * __expf(pmx[r] - gmx) + smo * __expf(mxo - gmx));
#pragma unroll
    for (int n = 0; n < 8; n++) {
      int m = gh * 128 + 16 * n + c15;
      float e = Ebase[(size_t)t * D_ + m];
      Pt[t * 264 + m] = f2bf(zac[n][r] * sc * e);
    }
  }
  __syncthreads();

  // P5: W = mask(P~ @ U^T); wave (tw,gh) computes tau-tiles {2gh,2gh+1},
  // accumulating over all m via 4 staged 64-m quarters (Ust).
  {
    f32x4 wac[2];
    wac[0] = zero4(); wac[1] = zero4();
    for (int mq = 0; mq < 4; mq++) {
      {
        int mloc = tid >> 3, th = tid & 7;  // 512 thr: 64 m x 8 tau-chunks
        s16x8 v = *(const s16x8*)(Uc + (size_t)(mq * 64 + mloc) * C_ + th * 8);
#pragma unroll
        for (int j = 0; j < 8; j++)
          Ust[(th * 8 + j) * 72 + mloc] = (u16)v[j];
      }
      __syncthreads();
#pragma unroll
      for (int ks = 0; ks < 2; ks++) {
        bf16x8 af = ld8(Pt, 264, 16 * tw, mq * 64 + 32 * ks, lane);
#pragma unroll
        for (int n = 0; n < 2; n++)
          wac[n] = MFMA(af, ld8(Ust, 72, 16 * (2 * gh + n), 32 * ks, lane), wac[n]);
      }
      __syncthreads();
    }
#pragma unroll
    for (int n = 0; n < 2; n++)
#pragma unroll
      for (int r = 0; r < 4; r++) {
        int t = 16 * tw + 4 * q4 + r, tau = 16 * (2 * gh + n) + c15;
        As[t * 72 + tau] = f2bf(tau <= t ? wac[n][r] : 0.f);
      }
  }
  __syncthreads();

  // P6: o = P~ @ Sv + W @ V^T; group gh handles vq in {2gh, 2gh+1} with its own
  // V^T staging buffer.
  {
    u16* Vst = gh ? Vst1 : Vst0;
    const int lt = tid & 255;  // thread index within group (waves are contiguous)
    for (int q = 0; q < 2; q++) {
      const int vq = 2 * gh + q;
      {
        int vloc = lt >> 2, th = lt & 3;
#pragma unroll 4
        for (int tt = 0; tt < 16; tt++) {
          int t = th * 16 + tt;
          Vst[vloc * 72 + t] = vg[(size_t)(R0 + t) * D_ + hb + vq * 64 + vloc];
        }
      }
      __syncthreads();
      f32x4 oac[4];
#pragma unroll
      for (int n = 0; n < 4; n++) oac[n] = zero4();
#pragma unroll
      for (int ks = 0; ks < 8; ks++) {
        bf16x8 af = ld8(Pt, 264, 16 * tw, 32 * ks, lane);
#pragma unroll
        for (int n = 0; n < 4; n++)
          oac[n] = MFMA(af, ld8(SvC + (size_t)vq * 64 * 256, 256, 16 * n, 32 * ks, lane),
                        oac[n]);
      }
#pragma unroll
      for (int ks = 0; ks < 2; ks++) {
        bf16x8 af = ld8(As, 72, 16 * tw, 32 * ks, lane);
#pragma unroll
        for (int n = 0; n < 4; n++)
          oac[n] = MFMA(af, ld8(Vst, 72, 16 * n, 32 * ks, lane), oac[n]);
      }
#pragma unroll
      for (int n = 0; n < 4; n++)
#pragma unroll
        for (int r = 0; r < 4; r++) {
          int t = 16 * tw + 4 * q4 + r;
          int vc = vq * 64 + 16 * n + c15;
          orw[(size_t)(R0 + t) * D_ + hb + vc] = f2bf(oac[n][r]);
        }
      __syncthreads();
    }
  }
}

extern "C" void kernel_launch(void* const* d_in, const int* in_sizes, int n_in,
                              void* d_out, int out_size, void* d_ws, size_t ws_size,
                              hipStream_t stream) {
  (void)in_sizes; (void)n_in; (void)out_size; (void)ws_size;
  const float* x   = (const float*)d_in[0];
  const float* nw  = (const float*)d_in[1];
  const float* wq  = (const float*)d_in[2];
  const float* wk  = (const float*)d_in[3];
  const float* wvp = (const float*)d_in[4];
  const float* wf  = (const float*)d_in[5];
  const float* gw  = (const float*)d_in[6];
  const float* wo  = (const float*)d_in[7];
  float* out = (float*)d_out;
  char* ws = (char*)d_ws;
  const size_t MB = 1024ull * 1024ull;
  u16*   hbuf = (u16*)(ws);             // 16MB h; later U_t; later o_normed
  u16*   qb   = (u16*)(ws + 16 * MB);   // 16MB
  u16*   kb   = (u16*)(ws + 32 * MB);   // 16MB
  u16*   vb   = (u16*)(ws + 48 * MB);   // 16MB
  float* gb   = (float*)(ws + 64 * MB); // 32MB fp32 linear g -> E in place
  u16*   SkB  = (u16*)(ws + 96 * MB);   // 64MB states [p][c][m][d]
  u16*   SvB  = (u16*)(ws + 160 * MB);  // 64MB states [p][c][v][m]
  float* Lam  = (float*)(ws + 224 * MB);// 0.5MB chunk decays
  u16*   orw  = (u16*)(ws + 226 * MB);  // 16MB raw attention output
  u16*   wqb  = (u16*)(ws + 242 * MB);  // 2MB bf16 weights
  u16*   wkb  = (u16*)(ws + 244 * MB);
  u16*   wvb  = (u16*)(ws + 246 * MB);
  u16*   wfb  = (u16*)(ws + 248 * MB);
  u16*   wob  = (u16*)(ws + 250 * MB);
  u16*   U_t  = hbuf;                   // 16MB [p][c][m][t] bf16 (aliases dead h)

  k_cvt5<<<dim3(5120), dim3(256), 0, stream>>>(wq, wk, wvp, wf, wo,
                                               wqb, wkb, wvb, wfb, wob);
  k_rmsnorm<<<dim3(8192), dim3(256), 0, stream>>>(x, nw, hbuf);
  k_gemm4<<<dim3(32, 16), dim3(256), 0, stream>>>(
      hbuf, wqb, wkb, wvb, wfb, qb, kb, vb, gb, 0);
  k_gemm4<<<dim3(32, 16), dim3(256), 0, stream>>>(
      hbuf, wqb, wkb, wvb, wfb, qb, kb, vb, gb, 4096);
  k_gates<<<dim3(NC_, 16), dim3(256), 0, stream>>>(gb, U_t, Lam);
  k_intra<<<dim3(NC_, 16), dim3(256), 0, stream>>>(kb, vb, U_t, Lam, SkB, SvB);
  k_scan<<<dim3(1024), dim3(256), 0, stream>>>(SkB, SvB, Lam);
  k_out<<<dim3(NC_, 16), dim3(512), 0, stream>>>(qb, kb, vb, U_t, gb, SkB, SvB, orw);
  k_swishnorm<<<dim3(8192), dim3(256), 0, stream>>>(orw, gw, hbuf);
  k_gemmO<<<dim3(64, 8), dim3(256), 0, stream>>>(hbuf, wob, out);
}

// Round 11
// 478.275 us; speedup vs baseline: 1.0178x; 1.0178x over previous
//
#include <hip/hip_runtime.h>
#include <hip/hip_bf16.h>

typedef unsigned short u16;
typedef unsigned int u32;

using bf16x8 = __bf16 __attribute__((ext_vector_type(8)));
using s16x8  = short  __attribute__((ext_vector_type(8)));
using f32x4  = float  __attribute__((ext_vector_type(4)));

#define DEV static __device__ __forceinline__

constexpr int T_ = 2048, D_ = 1024;
constexpr int C_ = 64, NC_ = 32;   // chunk length / count
constexpr float EPS_ = 1e-5f;

DEV float bf2f(u16 u) { return __uint_as_float(((u32)u) << 16); }
DEV u16 f2bf(float f) {
  u32 u = __float_as_uint(f);
  return (u16)((u + 0x7fffu + ((u >> 16) & 1u)) >> 16);
}
DEV float swishf(float x) { return x / (1.f + __expf(-x)); }
DEV f32x4 zero4() { f32x4 z = {0.f, 0.f, 0.f, 0.f}; return z; }

// fragment loader: operand stored [outdim][contract] row-major, 16B/lane
DEV bf16x8 ld8(const u16* p, int ld, int r0, int k0, int lane) {
  return *(const bf16x8*)(p + (size_t)(r0 + (lane & 15)) * ld +
                          (size_t)(k0 + ((lane >> 4) << 3)));
}
DEV f32x4 MFMA(bf16x8 a, bf16x8 b, f32x4 c) {
  return __builtin_amdgcn_mfma_f32_16x16x32_bf16(a, b, c, 0, 0, 0);
}
// direct global->LDS DMA, 16B per lane; LDS dest = wave-uniform base + lane*16
DEV void gld_lds16(const void* g, void* l) {
  __builtin_amdgcn_global_load_lds(
      (const __attribute__((address_space(1))) unsigned int*)g,
      (__attribute__((address_space(3))) unsigned int*)l, 16, 0, 0);
}

// ---------------- K0+K1 fused: weight cvt (5x) + RMSNorm (one launch) ---------------
// blocks [0,5120): fp32->bf16 weight conversion; blocks [5120,13312): RMSNorm.
// Branch is block-uniform; bodies are the previously-verified k_cvt5/k_rmsnorm.
__global__ __launch_bounds__(256) void k_prep(
    const float* __restrict__ s0, const float* __restrict__ s1,
    const float* __restrict__ s2, const float* __restrict__ s3,
    const float* __restrict__ s4, u16* __restrict__ d0, u16* __restrict__ d1,
    u16* __restrict__ d2, u16* __restrict__ d3, u16* __restrict__ d4,
    const float* __restrict__ x, const float* __restrict__ w,
    u16* __restrict__ h) {
  const int bx = blockIdx.x, tid = threadIdx.x;
  if (bx < 5120) {
    const int wsel = bx >> 10;
    const float* s = (wsel == 0) ? s0 : (wsel == 1) ? s1 : (wsel == 2) ? s2
                     : (wsel == 3) ? s3 : s4;
    u16* d = (wsel == 0) ? d0 : (wsel == 1) ? d1 : (wsel == 2) ? d2
             : (wsel == 3) ? d3 : d4;
    const int i = (bx & 1023) * 256 + tid;
    float4 v = ((const float4*)s)[i];
    uint2 o;
    o.x = (u32)f2bf(v.x) | ((u32)f2bf(v.y) << 16);
    o.y = (u32)f2bf(v.z) | ((u32)f2bf(v.w) << 16);
    ((uint2*)d)[i] = o;
    return;
  }
  const int row = bx - 5120;
  float4 v = ((const float4*)(x + (size_t)row * D_))[tid];
  float ss = v.x * v.x + v.y * v.y + v.z * v.z + v.w * v.w;
#pragma unroll
  for (int d = 32; d >= 1; d >>= 1) ss += __shfl_xor(ss, d, 64);
  __shared__ float red[4];
  if ((tid & 63) == 0) red[tid >> 6] = ss;
  __syncthreads();
  float rs = rsqrtf((red[0] + red[1] + red[2] + red[3]) * (1.f / D_) + EPS_);
  float4 wv = ((const float4*)w)[tid];
  uint2 o;
  o.x = (u32)f2bf(v.x * rs * wv.x) | ((u32)f2bf(v.y * rs * wv.y) << 16);
  o.y = (u32)f2bf(v.z * rs * wv.z) | ((u32)f2bf(v.w * rs * wv.w) << 16);
  *(uint2*)(h + (size_t)row * D_ + tid * 4) = o;
}

// ---------------- K6: swish + RMSNorm (bf16 in -> bf16) ----------------
__global__ __launch_bounds__(256) void k_swishnorm(const u16* __restrict__ x,
                                                   const float* __restrict__ w,
                                                   u16* __restrict__ o) {
  const int row = blockIdx.x, tid = threadIdx.x;
  uint2 pk = *(const uint2*)(x + (size_t)row * D_ + tid * 4);
  float v0 = swishf(bf2f((u16)(pk.x & 0xffff))), v1 = swishf(bf2f((u16)(pk.x >> 16)));
  float v2 = swishf(bf2f((u16)(pk.y & 0xffff))), v3 = swishf(bf2f((u16)(pk.y >> 16)));
  float ss = v0 * v0 + v1 * v1 + v2 * v2 + v3 * v3;
#pragma unroll
  for (int d = 32; d >= 1; d >>= 1) ss += __shfl_xor(ss, d, 64);
  __shared__ float red[4];
  if ((tid & 63) == 0) red[tid >> 6] = ss;
  __syncthreads();
  float rs = rsqrtf((red[0] + red[1] + red[2] + red[3]) * (1.f / D_) + EPS_);
  float4 wv = ((const float4*)w)[tid];
  uint2 ov;
  ov.x = (u32)f2bf(v0 * rs * wv.x) | ((u32)f2bf(v1 * rs * wv.y) << 16);
  ov.y = (u32)f2bf(v2 * rs * wv.z) | ((u32)f2bf(v3 * rs * wv.w) << 16);
  *(uint2*)(o + (size_t)row * D_ + tid * 4) = ov;
}

// ---------------- K2: fused 4-weight projection GEMM, counted-vmcnt pipeline --------
// R5's proven version (146.2 us), single (64,16) launch (R7/R10 split cost ~8us).
#define WAITV6() asm volatile("s_waitcnt vmcnt(6)" ::: "memory")
#define WAITV0() asm volatile("s_waitcnt vmcnt(0)" ::: "memory")
__global__ __launch_bounds__(256, 2) void k_gemm4(
    const u16* __restrict__ A, const u16* __restrict__ w0,
    const u16* __restrict__ w1, const u16* __restrict__ w2,
    const u16* __restrict__ w3, u16* __restrict__ oq, u16* __restrict__ okk,
    u16* __restrict__ ov, float* __restrict__ og) {
  __shared__ __align__(16) u16 As[3][128 * 32];   // 3 x 8KB
  __shared__ __align__(16) u16 Bs[3][4][64 * 32]; // 3 x 16KB  (72KB total)
  const int m0 = blockIdx.x * 128, n0 = blockIdx.y * 64;
  const int tid = threadIdx.x, lane = tid & 63, wvi = tid >> 6;
  f32x4 acc[4][2][4];  // [weight][mi][nj]
#pragma unroll
  for (int w = 0; w < 4; w++)
#pragma unroll
    for (int i = 0; i < 2; i++)
#pragma unroll
      for (int j = 0; j < 4; j++) acc[w][i][j] = zero4();
  const int srow = tid >> 2, scb = (tid & 3) * 8;
  const u16* Ag = A + (size_t)(m0 + srow) * 1024 + scb;
  const u16* Wg0 = w0 + (size_t)(n0 + srow) * 1024 + scb;
  const u16* Wg1 = w1 + (size_t)(n0 + srow) * 1024 + scb;
  const u16* Wg2 = w2 + (size_t)(n0 + srow) * 1024 + scb;
  const u16* Wg3 = w3 + (size_t)(n0 + srow) * 1024 + scb;
  const int sofs = (wvi * 16) * 32;  // this wave's 16-row slice in each tile

  auto stage = [&](int buf, int kk) {
    gld_lds16(Ag + kk, &As[buf][sofs]);
    gld_lds16(Ag + kk + 64 * 1024, &As[buf][sofs + 64 * 32]);
    gld_lds16(Wg0 + kk, &Bs[buf][0][sofs]);
    gld_lds16(Wg1 + kk, &Bs[buf][1][sofs]);
    gld_lds16(Wg2 + kk, &Bs[buf][2][sofs]);
    gld_lds16(Wg3 + kk, &Bs[buf][3][sofs]);
  };
  auto compute = [&](int buf) {
    bf16x8 af[2];
#pragma unroll
    for (int i = 0; i < 2; i++)
      af[i] = ld8(As[buf], 32, wvi * 32 + 16 * i, 0, lane);
#pragma unroll
    for (int w = 0; w < 4; w++) {
      bf16x8 bfr[4];
#pragma unroll
      for (int j = 0; j < 4; j++) bfr[j] = ld8(Bs[buf][w], 32, 16 * j, 0, lane);
#pragma unroll
      for (int i = 0; i < 2; i++)
#pragma unroll
        for (int j = 0; j < 4; j++) acc[w][i][j] = MFMA(af[i], bfr[j], acc[w][i][j]);
    }
  };

  stage(0, 0);
  stage(1, 32);
  int b0 = 0, b1 = 1, b2 = 2;
  for (int t = 0; t < 32; ++t) {
    if (t < 31) { WAITV6(); } else { WAITV0(); }
    __builtin_amdgcn_sched_barrier(0);
    __builtin_amdgcn_s_barrier();       // all waves' stage(t) landed; reads of t-1 done
    __builtin_amdgcn_sched_barrier(0);
    if (t + 2 < 32) stage(b2, (t + 2) * 32);  // issue-early prefetch into freed buffer
    __builtin_amdgcn_s_setprio(1);
    compute(b0);
    __builtin_amdgcn_s_setprio(0);
    int tmp = b0; b0 = b1; b1 = b2; b2 = tmp;  // rotate buffers
  }
  const int q4 = lane >> 4, c15 = lane & 15;
#pragma unroll
  for (int w = 0; w < 4; w++)
#pragma unroll
    for (int i = 0; i < 2; i++)
#pragma unroll
      for (int j = 0; j < 4; j++)
#pragma unroll
        for (int r = 0; r < 4; r++) {
          int grow = m0 + wvi * 32 + 16 * i + 4 * q4 + r;
          int gcol = n0 + 16 * j + c15;
          size_t idx = (size_t)grow * 1024 + gcol;
          float val = acc[w][i][j][r];
          if (w < 3) {
            u16* o = (w == 0) ? oq : (w == 1) ? okk : ov;
            o[idx] = f2bf(swishf(val));
          } else {
            float g = (val >= 0.f) ? -log1pf(__expf(-val))
                                   : (val - log1pf(__expf(val)));
            og[idx] = g * (1.0f / 16.0f);
          }
        }
}

// ---------------- K7: round-3 known-good 128x128 GEMM (final projection) ----------------
__global__ __launch_bounds__(256) void k_gemmO(const u16* __restrict__ A,
                                               const u16* __restrict__ W,
                                               float* __restrict__ ofin) {
  __shared__ __align__(16) u16 As[128 * 32];
  __shared__ __align__(16) u16 Bs[128 * 32];
  const int m0 = blockIdx.x * 128, n0 = blockIdx.y * 128;
  const int tid = threadIdx.x, lane = tid & 63, wvi = tid >> 6;
  const int wr = wvi >> 1, wc = wvi & 1;
  f32x4 acc[4][4];
#pragma unroll
  for (int i = 0; i < 4; i++)
#pragma unroll
    for (int j = 0; j < 4; j++) acc[i][j] = zero4();
  const int srow = tid >> 2, scb = (tid & 3) * 8;
  const u16* Ag = A + (size_t)(m0 + srow) * 1024 + scb;
  const u16* Wg = W + (size_t)(n0 + srow) * 1024 + scb;
  u16* AsW = As + (wvi * 16) * 32;
  u16* BsW = Bs + (wvi * 16) * 32;
  for (int kk = 0; kk < 1024; kk += 32) {
    gld_lds16(Ag + kk, AsW);
    gld_lds16(Ag + kk + 64 * 1024, AsW + 64 * 32);
    gld_lds16(Wg + kk, BsW);
    gld_lds16(Wg + kk + 64 * 1024, BsW + 64 * 32);
    __syncthreads();
    bf16x8 af[4], bfr[4];
#pragma unroll
    for (int i = 0; i < 4; i++) af[i] = ld8(As, 32, wr * 64 + 16 * i, 0, lane);
#pragma unroll
    for (int j = 0; j < 4; j++) bfr[j] = ld8(Bs, 32, wc * 64 + 16 * j, 0, lane);
#pragma unroll
    for (int i = 0; i < 4; i++)
#pragma unroll
      for (int j = 0; j < 4; j++) acc[i][j] = MFMA(af[i], bfr[j], acc[i][j]);
    __syncthreads();
  }
  const int q4 = lane >> 4, c15 = lane & 15;
#pragma unroll
  for (int i = 0; i < 4; i++)
#pragma unroll
    for (int j = 0; j < 4; j++)
#pragma unroll
      for (int r = 0; r < 4; r++) {
        int grow = m0 + wr * 64 + 16 * i + 4 * q4 + r;
        int gcol = n0 + wc * 64 + 16 * j + c15;
        ofin[(size_t)grow * 1024 + gcol] = acc[i][j][r];
      }
}

// ---------------- K2b: gates ----------------
__global__ __launch_bounds__(256) void k_gates(float* __restrict__ g_inout,
                                               u16* __restrict__ U_t,
                                               float* __restrict__ Lam) {
  const int c = blockIdx.x, p = blockIdx.y, tid = threadIdx.x;  // tid = m
  const int b = p >> 2, hh = p & 3;
  const int R0 = b * T_ + c * C_, hb = hh * 256;
  float ga = 0.f, ea = 1.f;
  short ubuf[C_];
#pragma unroll
  for (int t = 0; t < C_; t++) {
    size_t gi = (size_t)(R0 + t) * D_ + hb + tid;
    float gv = g_inout[gi];
    ga += gv;
    ea = __expf(ga);
    ubuf[t] = (short)f2bf((1.f - __expf(gv)) * __expf(-ga));
    g_inout[gi] = ea;  // E in place
  }
  Lam[((size_t)p * NC_ + c) * 256 + tid] = ea;
  u16* up = U_t + ((size_t)p * NC_ + c) * (256 * C_) + (size_t)tid * C_;
#pragma unroll
  for (int i = 0; i < 8; i++) {
    s16x8 w;
#pragma unroll
    for (int j = 0; j < 8; j++) w[j] = ubuf[i * 8 + j];
    *(s16x8*)(up + i * 8) = w;
  }
}

// ---------------- K3: per-chunk intra states ----------------
__global__ __launch_bounds__(256) void k_intra(
    const u16* __restrict__ kg, const u16* __restrict__ vg,
    const u16* __restrict__ U_t, const float* __restrict__ Lam,
    u16* __restrict__ Sk, u16* __restrict__ Sv) {
  __shared__ __align__(16) u16 KV[256 * 72];   // K^T then V^T  [d/v][tau]
  __shared__ float LamH[256];
  const int c = blockIdx.x, p = blockIdx.y;
  const int b = p >> 2, hh = p & 3;
  const int R0 = b * T_ + c * C_, hb = hh * 256;
  const int tid = threadIdx.x, lane = tid & 63, wvi = tid >> 6;
  const int q4 = lane >> 4, c15 = lane & 15;
  const size_t chunk = (size_t)p * NC_ + c;
  const u16* Uc = U_t + chunk * (256 * C_);  // [m][64]
  const size_t scBase = chunk * (256 * 256);

  LamH[tid] = Lam[chunk * 256 + tid];
  // stage K^T
  for (int t = 0; t < C_; t++)
    KV[tid * 72 + t] = kg[(size_t)(R0 + t) * D_ + hb + tid];
  __syncthreads();

  // Hk^T: [256 m][256 d]; wave wvi owns m rows [64*wvi, +64)
  for (int cb = 0; cb < 4; cb++) {
    f32x4 acc[4][4];
#pragma unroll
    for (int i = 0; i < 4; i++)
#pragma unroll
      for (int j = 0; j < 4; j++) acc[i][j] = zero4();
#pragma unroll
    for (int ks = 0; ks < 2; ks++) {
      bf16x8 af[4], bfr[4];
#pragma unroll
      for (int i = 0; i < 4; i++) af[i] = ld8(Uc, C_, 64 * wvi + 16 * i, 32 * ks, lane);
#pragma unroll
      for (int j = 0; j < 4; j++) bfr[j] = ld8(KV, 72, 64 * cb + 16 * j, 32 * ks, lane);
#pragma unroll
      for (int i = 0; i < 4; i++)
#pragma unroll
        for (int j = 0; j < 4; j++) acc[i][j] = MFMA(af[i], bfr[j], acc[i][j]);
    }
#pragma unroll
    for (int i = 0; i < 4; i++)
#pragma unroll
      for (int j = 0; j < 4; j++)
#pragma unroll
        for (int r = 0; r < 4; r++) {
          int ml = 64 * wvi + 16 * i + 4 * q4 + r;
          int dd = 64 * cb + 16 * j + c15;
          Sk[scBase + (size_t)ml * 256 + dd] = f2bf(acc[i][j][r] * LamH[ml]);
        }
  }
  __syncthreads();

  // stage V^T
  for (int t = 0; t < C_; t++)
    KV[tid * 72 + t] = vg[(size_t)(R0 + t) * D_ + hb + tid];
  __syncthreads();

  // Hv^T: [256 v][256 m]; wave wvi owns v rows [64*wvi, +64)
  for (int cb = 0; cb < 4; cb++) {
    f32x4 acc[4][4];
#pragma unroll
    for (int i = 0; i < 4; i++)
#pragma unroll
      for (int j = 0; j < 4; j++) acc[i][j] = zero4();
#pragma unroll
    for (int ks = 0; ks < 2; ks++) {
      bf16x8 af[4], bfr[4];
#pragma unroll
      for (int i = 0; i < 4; i++) af[i] = ld8(KV, 72, 64 * wvi + 16 * i, 32 * ks, lane);
#pragma unroll
      for (int j = 0; j < 4; j++) bfr[j] = ld8(Uc, C_, 64 * cb + 16 * j, 32 * ks, lane);
#pragma unroll
      for (int i = 0; i < 4; i++)
#pragma unroll
        for (int j = 0; j < 4; j++) acc[i][j] = MFMA(af[i], bfr[j], acc[i][j]);
    }
#pragma unroll
    for (int i = 0; i < 4; i++)
#pragma unroll
      for (int j = 0; j < 4; j++)
#pragma unroll
        for (int r = 0; r < 4; r++) {
          int vv = 64 * wvi + 16 * i + 4 * q4 + r;
          int ml = 64 * cb + 16 * j + c15;
          Sv[scBase + (size_t)vv * 256 + ml] = f2bf(acc[i][j][r] * LamH[ml]);
        }
  }
}

// ---------------- K4: chunk-prefix scan (entering state per chunk, in place) ----------------
__global__ __launch_bounds__(256) void k_scan(u16* __restrict__ Sk,
                                              u16* __restrict__ Sv,
                                              const float* __restrict__ Lam) {
  const int gid = blockIdx.x * 256 + threadIdx.x;  // 0..262143
  const int st = gid >> 17;
  const int w = gid & 131071;
  const int p = w >> 13;
  const int r = (w >> 5) & 255;
  const int c0 = (w & 31) * 8;
  u16* S = st ? Sv : Sk;
  const size_t base = (size_t)p * NC_ * 65536 + (size_t)r * 256 + c0;
  const float* Lp = Lam + (size_t)p * NC_ * 256;
  float acc[8] = {0, 0, 0, 0, 0, 0, 0, 0};
  for (int c = 0; c < NC_; c++) {
    s16x8 in = *(const s16x8*)(S + base + (size_t)c * 65536);
    s16x8 ov;
#pragma unroll
    for (int j = 0; j < 8; j++) ov[j] = (short)f2bf(acc[j]);
    *(s16x8*)(S + base + (size_t)c * 65536) = ov;  // entering state S_c
    if (st == 0) {
      float lam = Lp[c * 256 + r];
#pragma unroll
      for (int j = 0; j < 8; j++) acc[j] = acc[j] * lam + bf2f((u16)in[j]);
    } else {
#pragma unroll
      for (int j = 0; j < 8; j++) {
        float lam = Lp[c * 256 + c0 + j];
        acc[j] = acc[j] * lam + bf2f((u16)in[j]);
      }
    }
  }
}

// ---------------- K5: per-chunk output (R9 version — best measured: 90.6 us) --------
__global__ __launch_bounds__(256) void k_out(
    const u16* __restrict__ qg, const u16* __restrict__ kg,
    const u16* __restrict__ vg, const u16* __restrict__ U_t,
    const float* __restrict__ Eg, const u16* __restrict__ Sk,
    const u16* __restrict__ Sv, u16* __restrict__ orw) {
  __shared__ __align__(16) char lds[52224];
  u16* As = (u16*)lds;                // [64][72]: masked QK^T, later W
  u16* Pt = (u16*)(lds + 9216);       // [64][264]: P~
  u16* UnH = (u16*)(lds + 43008);     // [64][72]: U^T quarter (P5)
  u16* VxH = (u16*)(lds + 43008);     // [64][72]: V^T quarter (P6)

  const int c = blockIdx.x, p = blockIdx.y;
  const int b = p >> 2, hh = p & 3;
  const int R0 = b * T_ + c * C_, hb = hh * 256;
  const int tid = threadIdx.x, lane = tid & 63, wvi = tid >> 6;
  const int q4 = lane >> 4, c15 = lane & 15;
  const u16* qbase = qg + (size_t)R0 * D_ + hb;
  const u16* kbase = kg + (size_t)R0 * D_ + hb;
  const float* Ebase = Eg + (size_t)R0 * D_ + hb;  // E linear [t][1024] window
  const size_t chunk = (size_t)p * NC_ + c;
  const u16* SkC = Sk + chunk * 65536;
  const u16* SvC = Sv + chunk * 65536;
  const u16* Uc = U_t + chunk * (256 * C_);   // [m][64]

  // P1: masked QK^T
  {
    f32x4 acc[4];
#pragma unroll
    for (int n = 0; n < 4; n++) acc[n] = zero4();
#pragma unroll
    for (int ks = 0; ks < 8; ks++) {
      bf16x8 af = ld8(qbase, D_, 16 * wvi, 32 * ks, lane);
#pragma unroll
      for (int n = 0; n < 4; n++)
        acc[n] = MFMA(af, ld8(kbase, D_, 16 * n, 32 * ks, lane), acc[n]);
    }
#pragma unroll
    for (int n = 0; n < 4; n++)
#pragma unroll
      for (int r = 0; r < 4; r++) {
        int t = 16 * wvi + 4 * q4 + r, tau = 16 * n + c15;
        As[t * 72 + tau] = f2bf(tau <= t ? acc[n][r] : 0.f);
      }
  }
  __syncthreads();

  // P2: z = E * (As@U + Q@Sk)  (E multiplied in, not retained)
  f32x4 zac[16];
#pragma unroll
  for (int mh = 0; mh < 2; mh++) {
#pragma unroll
    for (int n = 0; n < 8; n++) zac[mh * 8 + n] = zero4();
#pragma unroll
    for (int ks = 0; ks < 2; ks++) {
      bf16x8 af = ld8(As, 72, 16 * wvi, 32 * ks, lane);
#pragma unroll
      for (int n = 0; n < 8; n++)
        zac[mh * 8 + n] = MFMA(af, ld8(Uc, C_, mh * 128 + 16 * n, 32 * ks, lane),
                               zac[mh * 8 + n]);
    }
#pragma unroll
    for (int ks = 0; ks < 8; ks++) {
      bf16x8 af = ld8(qbase, D_, 16 * wvi, 32 * ks, lane);
#pragma unroll
      for (int n = 0; n < 8; n++)
        zac[mh * 8 + n] = MFMA(
            af, ld8(SkC + (size_t)mh * 128 * 256, 256, 16 * n, 32 * ks, lane),
            zac[mh * 8 + n]);
    }
#pragma unroll
    for (int n = 0; n < 8; n++)
#pragma unroll
      for (int r = 0; r < 4; r++) {
        int t = 16 * wvi + 4 * q4 + r;
        zac[mh * 8 + n][r] *= Ebase[(size_t)t * D_ + mh * 128 + 16 * n + c15];
      }
  }

  // P3: row softmax (16-lane groups); P~ = p * E with E reloaded at store
  float invR[4];
#pragma unroll
  for (int r = 0; r < 4; r++) {
    float mx = -3.0e38f;
#pragma unroll
    for (int i = 0; i < 16; i++) mx = fmaxf(mx, zac[i][r]);
    mx = fmaxf(mx, __shfl_xor(mx, 1, 64));
    mx = fmaxf(mx, __shfl_xor(mx, 2, 64));
    mx = fmaxf(mx, __shfl_xor(mx, 4, 64));
    mx = fmaxf(mx, __shfl_xor(mx, 8, 64));
    float sm = 0.f;
#pragma unroll
    for (int i = 0; i < 16; i++) {
      float e = __expf(zac[i][r] - mx);
      zac[i][r] = e;
      sm += e;
    }
    sm += __shfl_xor(sm, 1, 64);
    sm += __shfl_xor(sm, 2, 64);
    sm += __shfl_xor(sm, 4, 64);
    sm += __shfl_xor(sm, 8, 64);
    invR[r] = 1.f / sm;
  }
#pragma unroll
  for (int i = 0; i < 16; i++)
#pragma unroll
    for (int r = 0; r < 4; r++) {
      int t = 16 * wvi + 4 * q4 + r;
      int m = (i >> 3) * 128 + 16 * (i & 7) + c15;
      float e = Ebase[(size_t)t * D_ + m];
      Pt[t * 264 + m] = f2bf(zac[i][r] * invR[r] * e);
    }
  __syncthreads();

  // P5: W = mask(P~ @ U^T) -> As   (UnH staged per 64-m quarter from U_t)
  {
    f32x4 wac[4];
#pragma unroll
    for (int n = 0; n < 4; n++) wac[n] = zero4();
    for (int mq = 0; mq < 4; mq++) {
      {
        int mloc = tid >> 2, th = tid & 3;
        const u16* ur = Uc + (size_t)(mq * 64 + mloc) * C_ + th * 16;
#pragma unroll
        for (int tt = 0; tt < 2; tt++) {
          s16x8 v = *(const s16x8*)(ur + tt * 8);
#pragma unroll
          for (int j = 0; j < 8; j++)
            UnH[(th * 16 + tt * 8 + j) * 72 + mloc] = (u16)v[j];
        }
      }
      __syncthreads();
#pragma unroll
      for (int ks = 0; ks < 2; ks++) {
        bf16x8 af = ld8(Pt, 264, 16 * wvi, mq * 64 + 32 * ks, lane);
#pragma unroll
        for (int n = 0; n < 4; n++)
          wac[n] = MFMA(af, ld8(UnH, 72, 16 * n, 32 * ks, lane), wac[n]);
      }
      __syncthreads();
    }
#pragma unroll
    for (int n = 0; n < 4; n++)
#pragma unroll
      for (int r = 0; r < 4; r++) {
        int t = 16 * wvi + 4 * q4 + r, tau = 16 * n + c15;
        As[t * 72 + tau] = f2bf(tau <= t ? wac[n][r] : 0.f);
      }
  }
  __syncthreads();

  // P6: o = P~ @ Sv + W @ V^T   (V^T staged per 64-v quarter)
  for (int vq = 0; vq < 4; vq++) {
    {
      int vloc = tid >> 2, th = tid & 3;
#pragma unroll 4
      for (int tt = 0; tt < 16; tt++) {
        int t = th * 16 + tt;
        VxH[vloc * 72 + t] = vg[(size_t)(R0 + t) * D_ + hb + vq * 64 + vloc];
      }
    }
    __syncthreads();
    f32x4 oac[4];
#pragma unroll
    for (int n = 0; n < 4; n++) oac[n] = zero4();
#pragma unroll
    for (int ks = 0; ks < 8; ks++) {
      bf16x8 af = ld8(Pt, 264, 16 * wvi, 32 * ks, lane);
#pragma unroll
      for (int n = 0; n < 4; n++)
        oac[n] = MFMA(af, ld8(SvC + (size_t)vq * 64 * 256, 256, 16 * n, 32 * ks, lane), oac[n]);
    }
#pragma unroll
    for (int ks = 0; ks < 2; ks++) {
      bf16x8 af = ld8(As, 72, 16 * wvi, 32 * ks, lane);
#pragma unroll
      for (int n = 0; n < 4; n++)
        oac[n] = MFMA(af, ld8(VxH, 72, 16 * n, 32 * ks, lane), oac[n]);
    }
#pragma unroll
    for (int n = 0; n < 4; n++)
#pragma unroll
      for (int r = 0; r < 4; r++) {
        int t = 16 * wvi + 4 * q4 + r;
        int vc = vq * 64 + 16 * n + c15;
        orw[(size_t)(R0 + t) * D_ + hb + vc] = f2bf(oac[n][r]);
      }
    __syncthreads();
  }
}

extern "C" void kernel_launch(void* const* d_in, const int* in_sizes, int n_in,
                              void* d_out, int out_size, void* d_ws, size_t ws_size,
                              hipStream_t stream) {
  (void)in_sizes; (void)n_in; (void)out_size; (void)ws_size;
  const float* x   = (const float*)d_in[0];
  const float* nw  = (const float*)d_in[1];
  const float* wq  = (const float*)d_in[2];
  const float* wk  = (const float*)d_in[3];
  const float* wvp = (const float*)d_in[4];
  const float* wf  = (const float*)d_in[5];
  const float* gw  = (const float*)d_in[6];
  const float* wo  = (const float*)d_in[7];
  float* out = (float*)d_out;
  char* ws = (char*)d_ws;
  const size_t MB = 1024ull * 1024ull;
  u16*   hbuf = (u16*)(ws);             // 16MB h; later U_t; later o_normed
  u16*   qb   = (u16*)(ws + 16 * MB);   // 16MB
  u16*   kb   = (u16*)(ws + 32 * MB);   // 16MB
  u16*   vb   = (u16*)(ws + 48 * MB);   // 16MB
  float* gb   = (float*)(ws + 64 * MB); // 32MB fp32 linear g -> E in place
  u16*   SkB  = (u16*)(ws + 96 * MB);   // 64MB states [p][c][m][d]
  u16*   SvB  = (u16*)(ws + 160 * MB);  // 64MB states [p][c][v][m]
  float* Lam  = (float*)(ws + 224 * MB);// 0.5MB chunk decays
  u16*   orw  = (u16*)(ws + 226 * MB);  // 16MB raw attention output
  u16*   wqb  = (u16*)(ws + 242 * MB);  // 2MB bf16 weights
  u16*   wkb  = (u16*)(ws + 244 * MB);
  u16*   wvb  = (u16*)(ws + 246 * MB);
  u16*   wfb  = (u16*)(ws + 248 * MB);
  u16*   wob  = (u16*)(ws + 250 * MB);
  u16*   U_t  = hbuf;                   // 16MB [p][c][m][t] bf16 (aliases dead h)

  k_prep<<<dim3(13312), dim3(256), 0, stream>>>(
      wq, wk, wvp, wf, wo, wqb, wkb, wvb, wfb, wob, x, nw, hbuf);
  k_gemm4<<<dim3(64, 16), dim3(256), 0, stream>>>(
      hbuf, wqb, wkb, wvb, wfb, qb, kb, vb, gb);
  k_gates<<<dim3(NC_, 16), dim3(256), 0, stream>>>(gb, U_t, Lam);
  k_intra<<<dim3(NC_, 16), dim3(256), 0, stream>>>(kb, vb, U_t, Lam, SkB, SvB);
  k_scan<<<dim3(1024), dim3(256), 0, stream>>>(SkB, SvB, Lam);
  k_out<<<dim3(NC_, 16), dim3(256), 0, stream>>>(qb, kb, vb, U_t, gb, SkB, SvB, orw);
  k_swishnorm<<<dim3(8192), dim3(256), 0, stream>>>(orw, gw, hbuf);
  k_gemmO<<<dim3(64, 8), dim3(256), 0, stream>>>(hbuf, wob, out);
}

// Round 12
// 456.523 us; speedup vs baseline: 1.0663x; 1.0476x over previous
//
#include <hip/hip_runtime.h>
#include <hip/hip_bf16.h>

typedef unsigned short u16;
typedef unsigned int u32;

using bf16x8 = __bf16 __attribute__((ext_vector_type(8)));
using s16x8  = short  __attribute__((ext_vector_type(8)));
using f32x4  = float  __attribute__((ext_vector_type(4)));

#define DEV static __device__ __forceinline__

constexpr int T_ = 2048, D_ = 1024;
constexpr int C_ = 64, NC_ = 32;   // chunk length / count
constexpr float EPS_ = 1e-5f;

DEV float bf2f(u16 u) { return __uint_as_float(((u32)u) << 16); }
DEV u16 f2bf(float f) {
  u32 u = __float_as_uint(f);
  return (u16)((u + 0x7fffu + ((u >> 16) & 1u)) >> 16);
}
DEV float swishf(float x) { return x / (1.f + __expf(-x)); }
DEV f32x4 zero4() { f32x4 z = {0.f, 0.f, 0.f, 0.f}; return z; }

// fragment loader: operand stored [outdim][contract] row-major, 16B/lane
DEV bf16x8 ld8(const u16* p, int ld, int r0, int k0, int lane) {
  return *(const bf16x8*)(p + (size_t)(r0 + (lane & 15)) * ld +
                          (size_t)(k0 + ((lane >> 4) << 3)));
}
DEV f32x4 MFMA(bf16x8 a, bf16x8 b, f32x4 c) {
  return __builtin_amdgcn_mfma_f32_16x16x32_bf16(a, b, c, 0, 0, 0);
}
// direct global->LDS DMA, 16B per lane; LDS dest = wave-uniform base + lane*16
DEV void gld_lds16(const void* g, void* l) {
  __builtin_amdgcn_global_load_lds(
      (const __attribute__((address_space(1))) unsigned int*)g,
      (__attribute__((address_space(3))) unsigned int*)l, 16, 0, 0);
}

// ---------------- K0+K1 fused: weight cvt (5x) + RMSNorm (one launch) ---------------
__global__ __launch_bounds__(256) void k_prep(
    const float* __restrict__ s0, const float* __restrict__ s1,
    const float* __restrict__ s2, const float* __restrict__ s3,
    const float* __restrict__ s4, u16* __restrict__ d0, u16* __restrict__ d1,
    u16* __restrict__ d2, u16* __restrict__ d3, u16* __restrict__ d4,
    const float* __restrict__ x, const float* __restrict__ w,
    u16* __restrict__ h) {
  const int bx = blockIdx.x, tid = threadIdx.x;
  if (bx < 5120) {
    const int wsel = bx >> 10;
    const float* s = (wsel == 0) ? s0 : (wsel == 1) ? s1 : (wsel == 2) ? s2
                     : (wsel == 3) ? s3 : s4;
    u16* d = (wsel == 0) ? d0 : (wsel == 1) ? d1 : (wsel == 2) ? d2
             : (wsel == 3) ? d3 : d4;
    const int i = (bx & 1023) * 256 + tid;
    float4 v = ((const float4*)s)[i];
    uint2 o;
    o.x = (u32)f2bf(v.x) | ((u32)f2bf(v.y) << 16);
    o.y = (u32)f2bf(v.z) | ((u32)f2bf(v.w) << 16);
    ((uint2*)d)[i] = o;
    return;
  }
  const int row = bx - 5120;
  float4 v = ((const float4*)(x + (size_t)row * D_))[tid];
  float ss = v.x * v.x + v.y * v.y + v.z * v.z + v.w * v.w;
#pragma unroll
  for (int d = 32; d >= 1; d >>= 1) ss += __shfl_xor(ss, d, 64);
  __shared__ float red[4];
  if ((tid & 63) == 0) red[tid >> 6] = ss;
  __syncthreads();
  float rs = rsqrtf((red[0] + red[1] + red[2] + red[3]) * (1.f / D_) + EPS_);
  float4 wv = ((const float4*)w)[tid];
  uint2 o;
  o.x = (u32)f2bf(v.x * rs * wv.x) | ((u32)f2bf(v.y * rs * wv.y) << 16);
  o.y = (u32)f2bf(v.z * rs * wv.z) | ((u32)f2bf(v.w * rs * wv.w) << 16);
  *(uint2*)(h + (size_t)row * D_ + tid * 4) = o;
}

// ---------------- K6: swish + RMSNorm (bf16 in -> bf16) ----------------
__global__ __launch_bounds__(256) void k_swishnorm(const u16* __restrict__ x,
                                                   const float* __restrict__ w,
                                                   u16* __restrict__ o) {
  const int row = blockIdx.x, tid = threadIdx.x;
  uint2 pk = *(const uint2*)(x + (size_t)row * D_ + tid * 4);
  float v0 = swishf(bf2f((u16)(pk.x & 0xffff))), v1 = swishf(bf2f((u16)(pk.x >> 16)));
  float v2 = swishf(bf2f((u16)(pk.y & 0xffff))), v3 = swishf(bf2f((u16)(pk.y >> 16)));
  float ss = v0 * v0 + v1 * v1 + v2 * v2 + v3 * v3;
#pragma unroll
  for (int d = 32; d >= 1; d >>= 1) ss += __shfl_xor(ss, d, 64);
  __shared__ float red[4];
  if ((tid & 63) == 0) red[tid >> 6] = ss;
  __syncthreads();
  float rs = rsqrtf((red[0] + red[1] + red[2] + red[3]) * (1.f / D_) + EPS_);
  float4 wv = ((const float4*)w)[tid];
  uint2 ov;
  ov.x = (u32)f2bf(v0 * rs * wv.x) | ((u32)f2bf(v1 * rs * wv.y) << 16);
  ov.y = (u32)f2bf(v2 * rs * wv.z) | ((u32)f2bf(v3 * rs * wv.w) << 16);
  *(uint2*)(o + (size_t)row * D_ + tid * 4) = ov;
}

// ---------------- K2: fused 4-weight projection GEMM, counted-vmcnt pipeline --------
#define WAITV6() asm volatile("s_waitcnt vmcnt(6)" ::: "memory")
#define WAITV0() asm volatile("s_waitcnt vmcnt(0)" ::: "memory")
__global__ __launch_bounds__(256, 2) void k_gemm4(
    const u16* __restrict__ A, const u16* __restrict__ w0,
    const u16* __restrict__ w1, const u16* __restrict__ w2,
    const u16* __restrict__ w3, u16* __restrict__ oq, u16* __restrict__ okk,
    u16* __restrict__ ov, float* __restrict__ og) {
  __shared__ __align__(16) u16 As[3][128 * 32];   // 3 x 8KB
  __shared__ __align__(16) u16 Bs[3][4][64 * 32]; // 3 x 16KB  (72KB total)
  const int m0 = blockIdx.x * 128, n0 = blockIdx.y * 64;
  const int tid = threadIdx.x, lane = tid & 63, wvi = tid >> 6;
  f32x4 acc[4][2][4];  // [weight][mi][nj]
#pragma unroll
  for (int w = 0; w < 4; w++)
#pragma unroll
    for (int i = 0; i < 2; i++)
#pragma unroll
      for (int j = 0; j < 4; j++) acc[w][i][j] = zero4();
  const int srow = tid >> 2, scb = (tid & 3) * 8;
  const u16* Ag = A + (size_t)(m0 + srow) * 1024 + scb;
  const u16* Wg0 = w0 + (size_t)(n0 + srow) * 1024 + scb;
  const u16* Wg1 = w1 + (size_t)(n0 + srow) * 1024 + scb;
  const u16* Wg2 = w2 + (size_t)(n0 + srow) * 1024 + scb;
  const u16* Wg3 = w3 + (size_t)(n0 + srow) * 1024 + scb;
  const int sofs = (wvi * 16) * 32;  // this wave's 16-row slice in each tile

  auto stage = [&](int buf, int kk) {
    gld_lds16(Ag + kk, &As[buf][sofs]);
    gld_lds16(Ag + kk + 64 * 1024, &As[buf][sofs + 64 * 32]);
    gld_lds16(Wg0 + kk, &Bs[buf][0][sofs]);
    gld_lds16(Wg1 + kk, &Bs[buf][1][sofs]);
    gld_lds16(Wg2 + kk, &Bs[buf][2][sofs]);
    gld_lds16(Wg3 + kk, &Bs[buf][3][sofs]);
  };
  auto compute = [&](int buf) {
    bf16x8 af[2];
#pragma unroll
    for (int i = 0; i < 2; i++)
      af[i] = ld8(As[buf], 32, wvi * 32 + 16 * i, 0, lane);
#pragma unroll
    for (int w = 0; w < 4; w++) {
      bf16x8 bfr[4];
#pragma unroll
      for (int j = 0; j < 4; j++) bfr[j] = ld8(Bs[buf][w], 32, 16 * j, 0, lane);
#pragma unroll
      for (int i = 0; i < 2; i++)
#pragma unroll
        for (int j = 0; j < 4; j++) acc[w][i][j] = MFMA(af[i], bfr[j], acc[w][i][j]);
    }
  };

  stage(0, 0);
  stage(1, 32);
  int b0 = 0, b1 = 1, b2 = 2;
  for (int t = 0; t < 32; ++t) {
    if (t < 31) { WAITV6(); } else { WAITV0(); }
    __builtin_amdgcn_sched_barrier(0);
    __builtin_amdgcn_s_barrier();       // all waves' stage(t) landed; reads of t-1 done
    __builtin_amdgcn_sched_barrier(0);
    if (t + 2 < 32) stage(b2, (t + 2) * 32);  // issue-early prefetch into freed buffer
    __builtin_amdgcn_s_setprio(1);
    compute(b0);
    __builtin_amdgcn_s_setprio(0);
    int tmp = b0; b0 = b1; b1 = b2; b2 = tmp;  // rotate buffers
  }
  const int q4 = lane >> 4, c15 = lane & 15;
#pragma unroll
  for (int w = 0; w < 4; w++)
#pragma unroll
    for (int i = 0; i < 2; i++)
#pragma unroll
      for (int j = 0; j < 4; j++)
#pragma unroll
        for (int r = 0; r < 4; r++) {
          int grow = m0 + wvi * 32 + 16 * i + 4 * q4 + r;
          int gcol = n0 + 16 * j + c15;
          size_t idx = (size_t)grow * 1024 + gcol;
          float val = acc[w][i][j][r];
          if (w < 3) {
            u16* o = (w == 0) ? oq : (w == 1) ? okk : ov;
            o[idx] = f2bf(swishf(val));
          } else {
            float g = (val >= 0.f) ? -log1pf(__expf(-val))
                                   : (val - log1pf(__expf(val)));
            og[idx] = g * (1.0f / 16.0f);
          }
        }
}

// ---------------- K7: round-3 known-good 128x128 GEMM (final projection) ----------------
__global__ __launch_bounds__(256) void k_gemmO(const u16* __restrict__ A,
                                               const u16* __restrict__ W,
                                               float* __restrict__ ofin) {
  __shared__ __align__(16) u16 As[128 * 32];
  __shared__ __align__(16) u16 Bs[128 * 32];
  const int m0 = blockIdx.x * 128, n0 = blockIdx.y * 128;
  const int tid = threadIdx.x, lane = tid & 63, wvi = tid >> 6;
  const int wr = wvi >> 1, wc = wvi & 1;
  f32x4 acc[4][4];
#pragma unroll
  for (int i = 0; i < 4; i++)
#pragma unroll
    for (int j = 0; j < 4; j++) acc[i][j] = zero4();
  const int srow = tid >> 2, scb = (tid & 3) * 8;
  const u16* Ag = A + (size_t)(m0 + srow) * 1024 + scb;
  const u16* Wg = W + (size_t)(n0 + srow) * 1024 + scb;
  u16* AsW = As + (wvi * 16) * 32;
  u16* BsW = Bs + (wvi * 16) * 32;
  for (int kk = 0; kk < 1024; kk += 32) {
    gld_lds16(Ag + kk, AsW);
    gld_lds16(Ag + kk + 64 * 1024, AsW + 64 * 32);
    gld_lds16(Wg + kk, BsW);
    gld_lds16(Wg + kk + 64 * 1024, BsW + 64 * 32);
    __syncthreads();
    bf16x8 af[4], bfr[4];
#pragma unroll
    for (int i = 0; i < 4; i++) af[i] = ld8(As, 32, wr * 64 + 16 * i, 0, lane);
#pragma unroll
    for (int j = 0; j < 4; j++) bfr[j] = ld8(Bs, 32, wc * 64 + 16 * j, 0, lane);
#pragma unroll
    for (int i = 0; i < 4; i++)
#pragma unroll
      for (int j = 0; j < 4; j++) acc[i][j] = MFMA(af[i], bfr[j], acc[i][j]);
    __syncthreads();
  }
  const int q4 = lane >> 4, c15 = lane & 15;
#pragma unroll
  for (int i = 0; i < 4; i++)
#pragma unroll
    for (int j = 0; j < 4; j++)
#pragma unroll
      for (int r = 0; r < 4; r++) {
        int grow = m0 + wr * 64 + 16 * i + 4 * q4 + r;
        int gcol = n0 + wc * 64 + 16 * j + c15;
        ofin[(size_t)grow * 1024 + gcol] = acc[i][j][r];
      }
}

// ---------------- K2b: gates ----------------
__global__ __launch_bounds__(256) void k_gates(float* __restrict__ g_inout,
                                               u16* __restrict__ U_t,
                                               float* __restrict__ Lam) {
  const int c = blockIdx.x, p = blockIdx.y, tid = threadIdx.x;  // tid = m
  const int b = p >> 2, hh = p & 3;
  const int R0 = b * T_ + c * C_, hb = hh * 256;
  float ga = 0.f, ea = 1.f;
  short ubuf[C_];
#pragma unroll
  for (int t = 0; t < C_; t++) {
    size_t gi = (size_t)(R0 + t) * D_ + hb + tid;
    float gv = g_inout[gi];
    ga += gv;
    ea = __expf(ga);
    ubuf[t] = (short)f2bf((1.f - __expf(gv)) * __expf(-ga));
    g_inout[gi] = ea;  // E in place
  }
  Lam[((size_t)p * NC_ + c) * 256 + tid] = ea;
  u16* up = U_t + ((size_t)p * NC_ + c) * (256 * C_) + (size_t)tid * C_;
#pragma unroll
  for (int i = 0; i < 8; i++) {
    s16x8 w;
#pragma unroll
    for (int j = 0; j < 8; j++) w[j] = ubuf[i * 8 + j];
    *(s16x8*)(up + i * 8) = w;
  }
}

// ---------------- K3: per-chunk intra states ----------------
__global__ __launch_bounds__(256) void k_intra(
    const u16* __restrict__ kg, const u16* __restrict__ vg,
    const u16* __restrict__ U_t, const float* __restrict__ Lam,
    u16* __restrict__ Sk, u16* __restrict__ Sv) {
  __shared__ __align__(16) u16 KV[256 * 72];   // K^T then V^T  [d/v][tau]
  __shared__ float LamH[256];
  const int c = blockIdx.x, p = blockIdx.y;
  const int b = p >> 2, hh = p & 3;
  const int R0 = b * T_ + c * C_, hb = hh * 256;
  const int tid = threadIdx.x, lane = tid & 63, wvi = tid >> 6;
  const int q4 = lane >> 4, c15 = lane & 15;
  const size_t chunk = (size_t)p * NC_ + c;
  const u16* Uc = U_t + chunk * (256 * C_);  // [m][64]
  const size_t scBase = chunk * (256 * 256);

  LamH[tid] = Lam[chunk * 256 + tid];
  // stage K^T
  for (int t = 0; t < C_; t++)
    KV[tid * 72 + t] = kg[(size_t)(R0 + t) * D_ + hb + tid];
  __syncthreads();

  // Hk^T: [256 m][256 d]; wave wvi owns m rows [64*wvi, +64)
  for (int cb = 0; cb < 4; cb++) {
    f32x4 acc[4][4];
#pragma unroll
    for (int i = 0; i < 4; i++)
#pragma unroll
      for (int j = 0; j < 4; j++) acc[i][j] = zero4();
#pragma unroll
    for (int ks = 0; ks < 2; ks++) {
      bf16x8 af[4], bfr[4];
#pragma unroll
      for (int i = 0; i < 4; i++) af[i] = ld8(Uc, C_, 64 * wvi + 16 * i, 32 * ks, lane);
#pragma unroll
      for (int j = 0; j < 4; j++) bfr[j] = ld8(KV, 72, 64 * cb + 16 * j, 32 * ks, lane);
#pragma unroll
      for (int i = 0; i < 4; i++)
#pragma unroll
        for (int j = 0; j < 4; j++) acc[i][j] = MFMA(af[i], bfr[j], acc[i][j]);
    }
#pragma unroll
    for (int i = 0; i < 4; i++)
#pragma unroll
      for (int j = 0; j < 4; j++)
#pragma unroll
        for (int r = 0; r < 4; r++) {
          int ml = 64 * wvi + 16 * i + 4 * q4 + r;
          int dd = 64 * cb + 16 * j + c15;
          Sk[scBase + (size_t)ml * 256 + dd] = f2bf(acc[i][j][r] * LamH[ml]);
        }
  }
  __syncthreads();

  // stage V^T
  for (int t = 0; t < C_; t++)
    KV[tid * 72 + t] = vg[(size_t)(R0 + t) * D_ + hb + tid];
  __syncthreads();

  // Hv^T: [256 v][256 m]; wave wvi owns v rows [64*wvi, +64)
  for (int cb = 0; cb < 4; cb++) {
    f32x4 acc[4][4];
#pragma unroll
    for (int i = 0; i < 4; i++)
#pragma unroll
      for (int j = 0; j < 4; j++) acc[i][j] = zero4();
#pragma unroll
    for (int ks = 0; ks < 2; ks++) {
      bf16x8 af[4], bfr[4];
#pragma unroll
      for (int i = 0; i < 4; i++) af[i] = ld8(KV, 72, 64 * wvi + 16 * i, 32 * ks, lane);
#pragma unroll
      for (int j = 0; j < 4; j++) bfr[j] = ld8(Uc, C_, 64 * cb + 16 * j, 32 * ks, lane);
#pragma unroll
      for (int i = 0; i < 4; i++)
#pragma unroll
        for (int j = 0; j < 4; j++) acc[i][j] = MFMA(af[i], bfr[j], acc[i][j]);
    }
#pragma unroll
    for (int i = 0; i < 4; i++)
#pragma unroll
      for (int j = 0; j < 4; j++)
#pragma unroll
        for (int r = 0; r < 4; r++) {
          int vv = 64 * wvi + 16 * i + 4 * q4 + r;
          int ml = 64 * cb + 16 * j + c15;
          Sv[scBase + (size_t)vv * 256 + ml] = f2bf(acc[i][j][r] * LamH[ml]);
        }
  }
}

// ---------------- K4: chunk-prefix scan (entering state per chunk, in place) ----------------
__global__ __launch_bounds__(256) void k_scan(u16* __restrict__ Sk,
                                              u16* __restrict__ Sv,
                                              const float* __restrict__ Lam) {
  const int gid = blockIdx.x * 256 + threadIdx.x;  // 0..262143
  const int st = gid >> 17;
  const int w = gid & 131071;
  const int p = w >> 13;
  const int r = (w >> 5) & 255;
  const int c0 = (w & 31) * 8;
  u16* S = st ? Sv : Sk;
  const size_t base = (size_t)p * NC_ * 65536 + (size_t)r * 256 + c0;
  const float* Lp = Lam + (size_t)p * NC_ * 256;
  float acc[8] = {0, 0, 0, 0, 0, 0, 0, 0};
  for (int c = 0; c < NC_; c++) {
    s16x8 in = *(const s16x8*)(S + base + (size_t)c * 65536);
    s16x8 ov;
#pragma unroll
    for (int j = 0; j < 8; j++) ov[j] = (short)f2bf(acc[j]);
    *(s16x8*)(S + base + (size_t)c * 65536) = ov;  // entering state S_c
    if (st == 0) {
      float lam = Lp[c * 256 + r];
#pragma unroll
      for (int j = 0; j < 8; j++) acc[j] = acc[j] * lam + bf2f((u16)in[j]);
    } else {
#pragma unroll
      for (int j = 0; j < 8; j++) {
        float lam = Lp[c * 256 + c0 + j];
        acc[j] = acc[j] * lam + bf2f((u16)in[j]);
      }
    }
  }
}

// ---------------- K5: per-chunk output (R12: coalesced Sk/Sv staging) ----------------
// R10's occupancy-doubling null ruled out TLP; theory now: the scattered direct
// ld8 global reads of Sk/Sv (lanes stride 512B -> ~32 cachelines/instr) saturate
// the per-CU memory-transaction pipe. Fix: stage each contiguous 32KB quarter of
// Sk (P2) / Sv (P6) via lane-consecutive 16B loads (1KB/wave-instr, 8 full lines)
// into a +16B-padded [64][264] LDS tile (conflict-free reads, same as Pt).
// q-fragments hoisted (qf[8], reused across quarters). P1/P3/P5 unchanged.
__global__ __launch_bounds__(256) void k_out(
    const u16* __restrict__ qg, const u16* __restrict__ kg,
    const u16* __restrict__ vg, const u16* __restrict__ U_t,
    const float* __restrict__ Eg, const u16* __restrict__ Sk,
    const u16* __restrict__ Sv, u16* __restrict__ orw) {
  __shared__ __align__(16) char lds[76800];
  u16* As  = (u16*)lds;                // [64][72]: masked QK^T, later W
  u16* Pt  = (u16*)(lds + 9216);       // [64][264]: P~
  u16* Sst = (u16*)(lds + 43008);      // [64][264]: Sk/Sv quarter (P2/P6a)
  u16* UnH = (u16*)(lds + 43008);      // [64][72]: U^T quarter (P5, alias)
  u16* VxH = (u16*)(lds + 43008);      // [64][72]: V^T quarter (P6b, alias)

  const int c = blockIdx.x, p = blockIdx.y;
  const int b = p >> 2, hh = p & 3;
  const int R0 = b * T_ + c * C_, hb = hh * 256;
  const int tid = threadIdx.x, lane = tid & 63, wvi = tid >> 6;
  const int q4 = lane >> 4, c15 = lane & 15;
  const u16* qbase = qg + (size_t)R0 * D_ + hb;
  const u16* kbase = kg + (size_t)R0 * D_ + hb;
  const float* Ebase = Eg + (size_t)R0 * D_ + hb;  // E linear [t][1024] window
  const size_t chunk = (size_t)p * NC_ + c;
  const u16* SkC = Sk + chunk * 65536;
  const u16* SvC = Sv + chunk * 65536;
  const u16* Uc = U_t + chunk * (256 * C_);   // [m][64]

  // coalesced 32KB quarter stage: lane-consecutive 16B -> padded [64][264] rows
  auto stageQ = [&](const u16* src) {
#pragma unroll
    for (int j = 0; j < 8; j++) {
      int byte = j * 4096 + tid * 16;
      int rr = byte >> 9, cb = byte & 511;
      s16x8 v = *(const s16x8*)((const char*)src + byte);
      *(s16x8*)((char*)Sst + rr * 528 + cb) = v;
    }
  };

  // P1: masked QK^T
  {
    f32x4 acc[4];
#pragma unroll
    for (int n = 0; n < 4; n++) acc[n] = zero4();
#pragma unroll
    for (int ks = 0; ks < 8; ks++) {
      bf16x8 af = ld8(qbase, D_, 16 * wvi, 32 * ks, lane);
#pragma unroll
      for (int n = 0; n < 4; n++)
        acc[n] = MFMA(af, ld8(kbase, D_, 16 * n, 32 * ks, lane), acc[n]);
    }
#pragma unroll
    for (int n = 0; n < 4; n++)
#pragma unroll
      for (int r = 0; r < 4; r++) {
        int t = 16 * wvi + 4 * q4 + r, tau = 16 * n + c15;
        As[t * 72 + tau] = f2bf(tau <= t ? acc[n][r] : 0.f);
      }
  }
  __syncthreads();

  // P2: z = E * (As@U + Q@Sk); Sk consumed via staged quarters
  bf16x8 qf[8];
#pragma unroll
  for (int ks = 0; ks < 8; ks++) qf[ks] = ld8(qbase, D_, 16 * wvi, 32 * ks, lane);
  f32x4 zac[16];
#pragma unroll
  for (int i = 0; i < 16; i++) zac[i] = zero4();
#pragma unroll
  for (int ks = 0; ks < 2; ks++) {
    bf16x8 af = ld8(As, 72, 16 * wvi, 32 * ks, lane);
#pragma unroll
    for (int i = 0; i < 16; i++)
      zac[i] = MFMA(af, ld8(Uc, C_, (i >> 3) * 128 + 16 * (i & 7), 32 * ks, lane),
                    zac[i]);
  }
  for (int mq = 0; mq < 4; mq++) {
    stageQ(SkC + (size_t)mq * 64 * 256);
    __syncthreads();
#pragma unroll
    for (int ks = 0; ks < 8; ks++)
#pragma unroll
      for (int nl = 0; nl < 4; nl++) {
        int zi = (mq >> 1) * 8 + (mq & 1) * 4 + nl;
        zac[zi] = MFMA(qf[ks], ld8(Sst, 264, 16 * nl, 32 * ks, lane), zac[zi]);
      }
    __syncthreads();
  }
#pragma unroll
  for (int i = 0; i < 16; i++)
#pragma unroll
    for (int r = 0; r < 4; r++) {
      int t = 16 * wvi + 4 * q4 + r;
      zac[i][r] *= Ebase[(size_t)t * D_ + (i >> 3) * 128 + 16 * (i & 7) + c15];
    }

  // P3: row softmax (16-lane groups); P~ = p * E with E reloaded at store
  float invR[4];
#pragma unroll
  for (int r = 0; r < 4; r++) {
    float mx = -3.0e38f;
#pragma unroll
    for (int i = 0; i < 16; i++) mx = fmaxf(mx, zac[i][r]);
    mx = fmaxf(mx, __shfl_xor(mx, 1, 64));
    mx = fmaxf(mx, __shfl_xor(mx, 2, 64));
    mx = fmaxf(mx, __shfl_xor(mx, 4, 64));
    mx = fmaxf(mx, __shfl_xor(mx, 8, 64));
    float sm = 0.f;
#pragma unroll
    for (int i = 0; i < 16; i++) {
      float e = __expf(zac[i][r] - mx);
      zac[i][r] = e;
      sm += e;
    }
    sm += __shfl_xor(sm, 1, 64);
    sm += __shfl_xor(sm, 2, 64);
    sm += __shfl_xor(sm, 4, 64);
    sm += __shfl_xor(sm, 8, 64);
    invR[r] = 1.f / sm;
  }
#pragma unroll
  for (int i = 0; i < 16; i++)
#pragma unroll
    for (int r = 0; r < 4; r++) {
      int t = 16 * wvi + 4 * q4 + r;
      int m = (i >> 3) * 128 + 16 * (i & 7) + c15;
      float e = Ebase[(size_t)t * D_ + m];
      Pt[t * 264 + m] = f2bf(zac[i][r] * invR[r] * e);
    }
  __syncthreads();

  // P5: W = mask(P~ @ U^T) -> As   (UnH staged per 64-m quarter from U_t)
  {
    f32x4 wac[4];
#pragma unroll
    for (int n = 0; n < 4; n++) wac[n] = zero4();
    for (int mq = 0; mq < 4; mq++) {
      {
        int mloc = tid >> 2, th = tid & 3;
        const u16* ur = Uc + (size_t)(mq * 64 + mloc) * C_ + th * 16;
#pragma unroll
        for (int tt = 0; tt < 2; tt++) {
          s16x8 v = *(const s16x8*)(ur + tt * 8);
#pragma unroll
          for (int j = 0; j < 8; j++)
            UnH[(th * 16 + tt * 8 + j) * 72 + mloc] = (u16)v[j];
        }
      }
      __syncthreads();
#pragma unroll
      for (int ks = 0; ks < 2; ks++) {
        bf16x8 af = ld8(Pt, 264, 16 * wvi, mq * 64 + 32 * ks, lane);
#pragma unroll
        for (int n = 0; n < 4; n++)
          wac[n] = MFMA(af, ld8(UnH, 72, 16 * n, 32 * ks, lane), wac[n]);
      }
      __syncthreads();
    }
#pragma unroll
    for (int n = 0; n < 4; n++)
#pragma unroll
      for (int r = 0; r < 4; r++) {
        int t = 16 * wvi + 4 * q4 + r, tau = 16 * n + c15;
        As[t * 72 + tau] = f2bf(tau <= t ? wac[n][r] : 0.f);
      }
  }
  __syncthreads();

  // P6: o = P~ @ Sv + W @ V^T   (Sv quarter staged coalesced; V^T scatter-staged)
  for (int vq = 0; vq < 4; vq++) {
    stageQ(SvC + (size_t)vq * 64 * 256);
    __syncthreads();
    f32x4 oac[4];
#pragma unroll
    for (int n = 0; n < 4; n++) oac[n] = zero4();
#pragma unroll
    for (int ks = 0; ks < 8; ks++) {
      bf16x8 af = ld8(Pt, 264, 16 * wvi, 32 * ks, lane);
#pragma unroll
      for (int n = 0; n < 4; n++)
        oac[n] = MFMA(af, ld8(Sst, 264, 16 * n, 32 * ks, lane), oac[n]);
    }
    __syncthreads();  // Sst reads done before V^T overwrites it
    {
      int vloc = tid >> 2, th = tid & 3;
#pragma unroll 4
      for (int tt = 0; tt < 16; tt++) {
        int t = th * 16 + tt;
        VxH[vloc * 72 + t] = vg[(size_t)(R0 + t) * D_ + hb + vq * 64 + vloc];
      }
    }
    __syncthreads();
#pragma unroll
    for (int ks = 0; ks < 2; ks++) {
      bf16x8 af = ld8(As, 72, 16 * wvi, 32 * ks, lane);
#pragma unroll
      for (int n = 0; n < 4; n++)
        oac[n] = MFMA(af, ld8(VxH, 72, 16 * n, 32 * ks, lane), oac[n]);
    }
#pragma unroll
    for (int n = 0; n < 4; n++)
#pragma unroll
      for (int r = 0; r < 4; r++) {
        int t = 16 * wvi + 4 * q4 + r;
        int vc = vq * 64 + 16 * n + c15;
        orw[(size_t)(R0 + t) * D_ + hb + vc] = f2bf(oac[n][r]);
      }
    __syncthreads();  // VxH reads done before next vq's stageQ overwrites
  }
}

extern "C" void kernel_launch(void* const* d_in, const int* in_sizes, int n_in,
                              void* d_out, int out_size, void* d_ws, size_t ws_size,
                              hipStream_t stream) {
  (void)in_sizes; (void)n_in; (void)out_size; (void)ws_size;
  const float* x   = (const float*)d_in[0];
  const float* nw  = (const float*)d_in[1];
  const float* wq  = (const float*)d_in[2];
  const float* wk  = (const float*)d_in[3];
  const float* wvp = (const float*)d_in[4];
  const float* wf  = (const float*)d_in[5];
  const float* gw  = (const float*)d_in[6];
  const float* wo  = (const float*)d_in[7];
  float* out = (float*)d_out;
  char* ws = (char*)d_ws;
  const size_t MB = 1024ull * 1024ull;
  u16*   hbuf = (u16*)(ws);             // 16MB h; later U_t; later o_normed
  u16*   qb   = (u16*)(ws + 16 * MB);   // 16MB
  u16*   kb   = (u16*)(ws + 32 * MB);   // 16MB
  u16*   vb   = (u16*)(ws + 48 * MB);   // 16MB
  float* gb   = (float*)(ws + 64 * MB); // 32MB fp32 linear g -> E in place
  u16*   SkB  = (u16*)(ws + 96 * MB);   // 64MB states [p][c][m][d]
  u16*   SvB  = (u16*)(ws + 160 * MB);  // 64MB states [p][c][v][m]
  float* Lam  = (float*)(ws + 224 * MB);// 0.5MB chunk decays
  u16*   orw  = (u16*)(ws + 226 * MB);  // 16MB raw attention output
  u16*   wqb  = (u16*)(ws + 242 * MB);  // 2MB bf16 weights
  u16*   wkb  = (u16*)(ws + 244 * MB);
  u16*   wvb  = (u16*)(ws + 246 * MB);
  u16*   wfb  = (u16*)(ws + 248 * MB);
  u16*   wob  = (u16*)(ws + 250 * MB);
  u16*   U_t  = hbuf;                   // 16MB [p][c][m][t] bf16 (aliases dead h)

  k_prep<<<dim3(13312), dim3(256), 0, stream>>>(
      wq, wk, wvp, wf, wo, wqb, wkb, wvb, wfb, wob, x, nw, hbuf);
  k_gemm4<<<dim3(64, 16), dim3(256), 0, stream>>>(
      hbuf, wqb, wkb, wvb, wfb, qb, kb, vb, gb);
  k_gates<<<dim3(NC_, 16), dim3(256), 0, stream>>>(gb, U_t, Lam);
  k_intra<<<dim3(NC_, 16), dim3(256), 0, stream>>>(kb, vb, U_t, Lam, SkB, SvB);
  k_scan<<<dim3(1024), dim3(256), 0, stream>>>(SkB, SvB, Lam);
  k_out<<<dim3(NC_, 16), dim3(256), 0, stream>>>(qb, kb, vb, U_t, gb, SkB, SvB, orw);
  k_swishnorm<<<dim3(8192), dim3(256), 0, stream>>>(orw, gw, hbuf);
  k_gemmO<<<dim3(64, 8), dim3(256), 0, stream>>>(hbuf, wob, out);
}